// Round 4
// baseline (231.185 us; speedup 1.0000x reference)
//
#include <hip/hip_runtime.h>
#include <hip/hip_bf16.h>

#define N_EXPERTS 8
#define T_TOKENS 32768
#define D 512            // D_IN == D_OUT
#define TILE 128
#define MAX_MTILES 264   // ceil((32768 + 8*127) / 128)
#define SORT_CAP (MAX_MTILES * TILE)   // 33792
#define GCX_BLOCKS (SORT_CAP / 4)                      // 8448
#define WCV_BLOCKS ((N_EXPERTS * D * D) / (256 * 8))   // 1024

typedef __bf16 bf16x8 __attribute__((ext_vector_type(8)));
typedef float  f32x4  __attribute__((ext_vector_type(4)));
typedef unsigned short u16x8 __attribute__((ext_vector_type(8)));

__device__ __forceinline__ unsigned short f2bf(float f) {
    unsigned int u = __float_as_uint(f);
    u += 0x7FFFu + ((u >> 16) & 1u);   // round-to-nearest-even
    return (unsigned short)(u >> 16);
}

__device__ __forceinline__ int pad_tile(int c) { return (c + TILE - 1) & ~(TILE - 1); }

// ---- pass 1: per-expert histogram ----
__global__ void hist_kernel(const int* __restrict__ p, int* __restrict__ counts) {
    __shared__ int h[N_EXPERTS];
    int tid = threadIdx.x;
    if (tid < N_EXPERTS) h[tid] = 0;
    __syncthreads();
    for (int t = blockIdx.x * blockDim.x + tid; t < T_TOKENS; t += gridDim.x * blockDim.x)
        atomicAdd(&h[p[t]], 1);
    __syncthreads();
    if (tid < N_EXPERTS) atomicAdd(&counts[tid], h[tid]);
}

// ---- pass 2: scatter token ids (two-level, low-contention) ----
// padded prefix computed in-register from counts (no offsets kernel)
__global__ void scatter_kernel(const int* __restrict__ p, const int* __restrict__ counts,
                               int* __restrict__ fill, int* __restrict__ sorted) {
    __shared__ int lcount[N_EXPERTS];
    __shared__ int lbase[N_EXPERTS];
    int tid = threadIdx.x;
    if (tid < N_EXPERTS) lcount[tid] = 0;
    __syncthreads();
    int t = blockIdx.x * blockDim.x + tid;
    int e = 0, lrank = 0;
    if (t < T_TOKENS) {
        e = p[t];
        lrank = atomicAdd(&lcount[e], 1);
    }
    __syncthreads();
    if (tid < N_EXPERTS)
        lbase[tid] = (lcount[tid] > 0) ? atomicAdd(&fill[tid], lcount[tid]) : 0;
    __syncthreads();
    if (t < T_TOKENS) {
        int base = 0;
#pragma unroll
        for (int i = 0; i < N_EXPERTS; i++)
            if (e > i) base += pad_tile(counts[i]);   // predicated add, no dyn array
        sorted[base + lbase[e] + lrank] = t;
    }
}

// ---- pass 3: fused gather x->sorted bf16 + convert W->bf16 ----
__global__ __launch_bounds__(256) void convert_kernel(
        const float* __restrict__ x, const float* __restrict__ W,
        const int* __restrict__ sorted, const int* __restrict__ counts,
        unsigned short* __restrict__ xs, unsigned short* __restrict__ Wb) {
    int bid = blockIdx.x;
    if (bid < GCX_BLOCKS) {
        int row = bid * 4 + (threadIdx.x >> 6);
        int total = 0;
#pragma unroll
        for (int i = 0; i < N_EXPERTS; i++) total += pad_tile(counts[i]);
        if (row >= total) return;
        int lane = threadIdx.x & 63;
        int tok = sorted[row];
        u16x8 o;
        if (tok >= 0) {
            const float4* src = (const float4*)(x + (size_t)tok * D + lane * 8);
            float4 a = src[0], b = src[1];
            o[0] = f2bf(a.x); o[1] = f2bf(a.y); o[2] = f2bf(a.z); o[3] = f2bf(a.w);
            o[4] = f2bf(b.x); o[5] = f2bf(b.y); o[6] = f2bf(b.z); o[7] = f2bf(b.w);
        } else {
            o = (u16x8)0;   // pad rows: zeros (MFMA'd but discarded)
        }
        *(u16x8*)&xs[(size_t)row * D + lane * 8] = o;
    } else {
        size_t i = ((size_t)(bid - GCX_BLOCKS) * 256 + threadIdx.x) * 8;
        const float4* s = (const float4*)(W + i);
        float4 a = s[0], b = s[1];
        u16x8 o;
        o[0] = f2bf(a.x); o[1] = f2bf(a.y); o[2] = f2bf(a.z); o[3] = f2bf(a.w);
        o[4] = f2bf(b.x); o[5] = f2bf(b.y); o[6] = f2bf(b.z); o[7] = f2bf(b.w);
        *(u16x8*)&Wb[i] = o;
    }
}

// ---- pass 4: grouped GEMM, NO LDS staging — fragments loaded global->VGPR.
// xs is sorted-contiguous, so each lane's A fragment (8 bf16) is one
// global_load_dwordx4; same for B. K-loop has NO barriers / vmcnt(0) drains:
// one-stage software pipeline, compiler emits fine-grained vmcnt(N).
__global__ __launch_bounds__(256) void moe_gemm_direct(
        const unsigned short* __restrict__ xs, const unsigned short* __restrict__ Wb,
        const float* __restrict__ bias, const int* __restrict__ counts,
        const int* __restrict__ sorted, float* __restrict__ out) {
    __shared__ int s_idx[TILE];
    int bn = blockIdx.x, bm = blockIdx.y;
    int row0 = bm * TILE;
    int total = 0, e = 0;
#pragma unroll
    for (int i = 0; i < N_EXPERTS; i++) {
        int sz = pad_tile(counts[i]);
        if (row0 >= total + sz) e = i + 1;
        total += sz;
    }
    if (row0 >= total) return;

    int tid = threadIdx.x;
    if (tid < TILE) s_idx[tid] = sorted[row0 + tid];
    __syncthreads();   // the only barrier in the kernel

    int wave = tid >> 6, lane = tid & 63;
    int wm = (wave >> 1) * 64, wn = (wave & 1) * 64;
    int lrow = lane & 15, lq = lane >> 4;

    const unsigned short* Ap = xs + (size_t)(row0 + wm + lrow) * D + lq * 8;
    const unsigned short* Bp = Wb + ((size_t)e * D + bn * TILE + wn + lrow) * D + lq * 8;

    f32x4 acc[4][4];
#pragma unroll
    for (int i = 0; i < 4; i++)
#pragma unroll
        for (int j = 0; j < 4; j++)
            acc[i][j] = (f32x4){0.f, 0.f, 0.f, 0.f};

    bf16x8 a0[4], b0[4], a1[4], b1[4];

#define LOADF(av, bv, ks) do {                                                  \
    _Pragma("unroll") for (int i = 0; i < 4; i++)                               \
        av[i] = *(const bf16x8*)(Ap + i * 16 * D + (ks) * 32);                  \
    _Pragma("unroll") for (int j = 0; j < 4; j++)                               \
        bv[j] = *(const bf16x8*)(Bp + j * 16 * D + (ks) * 32);                  \
} while (0)
#define MFMAF(av, bv) do {                                                      \
    _Pragma("unroll") for (int i = 0; i < 4; i++)                               \
    _Pragma("unroll") for (int j = 0; j < 4; j++)                               \
        acc[i][j] = __builtin_amdgcn_mfma_f32_16x16x32_bf16(                    \
            av[i], bv[j], acc[i][j], 0, 0, 0);                                  \
} while (0)

    LOADF(a0, b0, 0);
#pragma unroll 1
    for (int ks = 0; ks < 16; ks += 2) {
        LOADF(a1, b1, ks + 1);
        MFMAF(a0, b0);
        LOADF(a0, b0, ks + 2);   // ks=16 over-reads ~49KB into adjacent ws arrays: mapped, unused
        MFMAF(a1, b1);
    }
#undef LOADF
#undef MFMAF

    // epilogue: bias + scatter rows back by token id
    // C/D layout: col = lane&15 (n), row = (lane>>4)*4 + reg (m)
#pragma unroll
    for (int j = 0; j < 4; j++) {
        int ng = bn * TILE + wn + 16 * j + lrow;
        float bv = bias[e * D + ng];
#pragma unroll
        for (int i = 0; i < 4; i++) {
#pragma unroll
            for (int r = 0; r < 4; r++) {
                int mrow = wm + 16 * i + lq * 4 + r;
                int tok = s_idx[mrow];
                if (tok >= 0)
                    out[(size_t)tok * D + ng] = acc[i][j][r] + bv;
            }
        }
    }
}

// ---- fallback (small ws): fp32-load GEMM (round-2 style, counts-prefix) ----
__global__ __launch_bounds__(256) void moe_gemm_f32(
        const float* __restrict__ x, const float* __restrict__ W,
        const float* __restrict__ bias, const int* __restrict__ counts,
        const int* __restrict__ sorted, float* __restrict__ out) {
    __shared__ int s_idx[TILE];
    __shared__ unsigned short sA[TILE][64 + 8];
    __shared__ unsigned short sB[TILE][64 + 8];

    int bm = blockIdx.x, bn = blockIdx.y;
    int row0 = bm * TILE;
    int total = 0, e = 0;
#pragma unroll
    for (int i = 0; i < N_EXPERTS; i++) {
        int sz = pad_tile(counts[i]);
        if (row0 >= total + sz) e = i + 1;
        total += sz;
    }
    if (row0 >= total) return;

    int tid = threadIdx.x;
    if (tid < TILE) s_idx[tid] = sorted[row0 + tid];
    __syncthreads();

    const float* Wb = W + (size_t)e * D * D + (size_t)(bn * TILE) * D;

    f32x4 acc[4][4];
#pragma unroll
    for (int i = 0; i < 4; i++)
#pragma unroll
        for (int j = 0; j < 4; j++)
            acc[i][j] = (f32x4){0.f, 0.f, 0.f, 0.f};

    int wave = tid >> 6, lane = tid & 63;
    int wm = (wave >> 1) * 64, wn = (wave & 1) * 64;
    int lrow = lane & 15, lq = lane >> 4;

    for (int kk = 0; kk < D; kk += 64) {
#pragma unroll
        for (int i = 0; i < 8; i++) {
            int flat = tid + i * 256;
            int r = flat >> 4, c = (flat & 15) << 2;
            int tok = s_idx[r];
            float4 v = make_float4(0.f, 0.f, 0.f, 0.f);
            if (tok >= 0) v = *(const float4*)(x + (size_t)tok * D + kk + c);
            ushort4 w4;
            w4.x = f2bf(v.x); w4.y = f2bf(v.y); w4.z = f2bf(v.z); w4.w = f2bf(v.w);
            *(ushort4*)&sA[r][c] = w4;
        }
#pragma unroll
        for (int i = 0; i < 8; i++) {
            int flat = tid + i * 256;
            int r = flat >> 4, c = (flat & 15) << 2;
            float4 v = *(const float4*)(Wb + (size_t)r * D + kk + c);
            ushort4 w4;
            w4.x = f2bf(v.x); w4.y = f2bf(v.y); w4.z = f2bf(v.z); w4.w = f2bf(v.w);
            *(ushort4*)&sB[r][c] = w4;
        }
        __syncthreads();
#pragma unroll
        for (int ks = 0; ks < 2; ks++) {
            bf16x8 af[4], bfr[4];
#pragma unroll
            for (int i = 0; i < 4; i++)
                af[i] = *(const bf16x8*)&sA[wm + 16 * i + lrow][ks * 32 + lq * 8];
#pragma unroll
            for (int j = 0; j < 4; j++)
                bfr[j] = *(const bf16x8*)&sB[wn + 16 * j + lrow][ks * 32 + lq * 8];
#pragma unroll
            for (int i = 0; i < 4; i++)
#pragma unroll
                for (int j = 0; j < 4; j++)
                    acc[i][j] = __builtin_amdgcn_mfma_f32_16x16x32_bf16(
                        af[i], bfr[j], acc[i][j], 0, 0, 0);
        }
        __syncthreads();
    }

#pragma unroll
    for (int j = 0; j < 4; j++) {
        int ng = bn * TILE + wn + 16 * j + lrow;
        float bv = bias[e * D + ng];
#pragma unroll
        for (int i = 0; i < 4; i++) {
#pragma unroll
            for (int r = 0; r < 4; r++) {
                int mrow = wm + 16 * i + lq * 4 + r;
                int tok = s_idx[mrow];
                if (tok >= 0)
                    out[(size_t)tok * D + ng] = acc[i][j][r] + bv;
            }
        }
    }
}

extern "C" void kernel_launch(void* const* d_in, const int* in_sizes, int n_in,
                              void* d_out, int out_size, void* d_ws, size_t ws_size,
                              hipStream_t stream) {
    const float* x    = (const float*)d_in[0];
    const int*   part = (const int*)d_in[1];
    const float* W    = (const float*)d_in[2];
    const float* b    = (const float*)d_in[3];
    float* out = (float*)d_out;

    const size_t xs_elems = (size_t)SORT_CAP * D;        // bf16
    const size_t wb_elems = (size_t)N_EXPERTS * D * D;   // bf16
    const size_t fast_bytes = (xs_elems + wb_elems) * 2 + SORT_CAP * 4 + 32 * 4;

    if (ws_size >= fast_bytes) {
        unsigned short* xs = (unsigned short*)d_ws;
        unsigned short* Wb = xs + xs_elems;
        int* sorted = (int*)(Wb + wb_elems);   // after Wb: GEMM over-read lands here (mapped)
        int* counts = sorted + SORT_CAP;
        int* fill   = counts + N_EXPERTS;

        hipMemsetAsync(sorted, 0xFF, SORT_CAP * sizeof(int), stream);
        hipMemsetAsync(counts, 0, 2 * N_EXPERTS * sizeof(int), stream);

        hist_kernel<<<64, 256, 0, stream>>>(part, counts);
        scatter_kernel<<<(T_TOKENS + 255) / 256, 256, 0, stream>>>(part, counts, fill, sorted);
        convert_kernel<<<GCX_BLOCKS + WCV_BLOCKS, 256, 0, stream>>>(x, W, sorted, counts, xs, Wb);

        dim3 grid(D / TILE, MAX_MTILES);   // bn fastest: n-tiles of one m-tile adjacent
        moe_gemm_direct<<<grid, 256, 0, stream>>>(xs, Wb, b, counts, sorted, out);
    } else {
        int* sorted = (int*)d_ws;
        int* counts = sorted + SORT_CAP;
        int* fill   = counts + N_EXPERTS;

        hipMemsetAsync(sorted, 0xFF, SORT_CAP * sizeof(int), stream);
        hipMemsetAsync(counts, 0, 2 * N_EXPERTS * sizeof(int), stream);

        hist_kernel<<<64, 256, 0, stream>>>(part, counts);
        scatter_kernel<<<(T_TOKENS + 255) / 256, 256, 0, stream>>>(part, counts, fill, sorted);

        dim3 grid(MAX_MTILES, D / TILE);
        moe_gemm_f32<<<grid, 256, 0, stream>>>(x, W, b, counts, sorted, out);
    }
}

// Round 5
// 199.133 us; speedup vs baseline: 1.1610x; 1.1610x over previous
//
#include <hip/hip_runtime.h>
#include <hip/hip_bf16.h>

#define N_EXPERTS 8
#define T_TOKENS 32768
#define D 512            // D_IN == D_OUT
#define TILE 128
#define MAX_MTILES 264   // ceil((32768 + 8*127) / 128)
#define SORT_CAP (MAX_MTILES * TILE)   // 33792
#define GCX_BLOCKS (SORT_CAP / 4)                      // 8448
#define WCV_BLOCKS ((N_EXPERTS * D * D) / (256 * 8))   // 1024

// fragment-linear layout: 16-row x 32-k tile = 512 elems (1KB) contiguous,
// lane-major: elem_addr = rowtile*8192 + kblock*512 + lane*8 (+el)
// where lane = lq*16 + lrow, lrow = row&15, lq = (k>>3)&3.

typedef __bf16 bf16x8 __attribute__((ext_vector_type(8)));
typedef float  f32x4  __attribute__((ext_vector_type(4)));
typedef unsigned short u16x8 __attribute__((ext_vector_type(8)));

__device__ __forceinline__ unsigned short f2bf(float f) {
    unsigned int u = __float_as_uint(f);
    u += 0x7FFFu + ((u >> 16) & 1u);   // round-to-nearest-even
    return (unsigned short)(u >> 16);
}

__device__ __forceinline__ int pad_tile(int c) { return (c + TILE - 1) & ~(TILE - 1); }

// ---- pass 1: per-expert histogram ----
__global__ void hist_kernel(const int* __restrict__ p, int* __restrict__ counts) {
    __shared__ int h[N_EXPERTS];
    int tid = threadIdx.x;
    if (tid < N_EXPERTS) h[tid] = 0;
    __syncthreads();
    for (int t = blockIdx.x * blockDim.x + tid; t < T_TOKENS; t += gridDim.x * blockDim.x)
        atomicAdd(&h[p[t]], 1);
    __syncthreads();
    if (tid < N_EXPERTS) atomicAdd(&counts[tid], h[tid]);
}

// ---- pass 2: scatter token ids (two-level, low-contention) ----
__global__ void scatter_kernel(const int* __restrict__ p, const int* __restrict__ counts,
                               int* __restrict__ fill, int* __restrict__ sorted) {
    __shared__ int lcount[N_EXPERTS];
    __shared__ int lbase[N_EXPERTS];
    int tid = threadIdx.x;
    if (tid < N_EXPERTS) lcount[tid] = 0;
    __syncthreads();
    int t = blockIdx.x * blockDim.x + tid;
    int e = 0, lrank = 0;
    if (t < T_TOKENS) {
        e = p[t];
        lrank = atomicAdd(&lcount[e], 1);
    }
    __syncthreads();
    if (tid < N_EXPERTS)
        lbase[tid] = (lcount[tid] > 0) ? atomicAdd(&fill[tid], lcount[tid]) : 0;
    __syncthreads();
    if (t < T_TOKENS) {
        int base = 0;
#pragma unroll
        for (int i = 0; i < N_EXPERTS; i++)
            if (e > i) base += pad_tile(counts[i]);
        sorted[base + lbase[e] + lrank] = t;
    }
}

// ---- pass 3: fused gather x->sorted + convert W, writing FRAGMENT-LINEAR bf16 ----
__global__ __launch_bounds__(256) void convert_kernel(
        const float* __restrict__ x, const float* __restrict__ W,
        const int* __restrict__ sorted, const int* __restrict__ counts,
        unsigned short* __restrict__ xs, unsigned short* __restrict__ Wb) {
    int bid = blockIdx.x;
    int tid = threadIdx.x;
    if (bid < GCX_BLOCKS) {
        int row = bid * 4 + (tid >> 6);
        int total = 0;
#pragma unroll
        for (int i = 0; i < N_EXPERTS; i++) total += pad_tile(counts[i]);
        if (row >= total) return;
        int lane = tid & 63;
        int tok = sorted[row];
        u16x8 o;
        if (tok >= 0) {
            const float4* src = (const float4*)(x + (size_t)tok * D + lane * 8);
            float4 a = src[0], b = src[1];
            o[0] = f2bf(a.x); o[1] = f2bf(a.y); o[2] = f2bf(a.z); o[3] = f2bf(a.w);
            o[4] = f2bf(b.x); o[5] = f2bf(b.y); o[6] = f2bf(b.z); o[7] = f2bf(b.w);
        } else {
            o = (u16x8)0;   // pad rows: zeros (MFMA'd but discarded)
        }
        // lane covers k = lane*8..lane*8+7 -> kb = lane>>2, lq = lane&3
        int rt = row >> 4, lrow = row & 15;
        size_t waddr = (size_t)rt * 8192 + (size_t)(lane >> 2) * 512
                     + (size_t)((lane & 3) * 16 + lrow) * 8;
        *(u16x8*)&xs[waddr] = o;
    } else {
        size_t i = ((size_t)(bid - GCX_BLOCKS) * 256 + tid) * 8;   // flat W index
        const float4* s = (const float4*)(W + i);
        float4 a = s[0], b = s[1];
        u16x8 o;
        o[0] = f2bf(a.x); o[1] = f2bf(a.y); o[2] = f2bf(a.z); o[3] = f2bf(a.w);
        o[4] = f2bf(b.x); o[5] = f2bf(b.y); o[6] = f2bf(b.z); o[7] = f2bf(b.w);
        size_t eb = i & ~(size_t)262143;          // e*512*512
        int rem = (int)(i & 262143);
        int n = rem >> 9, c = rem & 511;
        size_t waddr = eb + (size_t)(n >> 4) * 8192 + (size_t)(c >> 5) * 512
                     + (size_t)(((c >> 3) & 3) * 16 + (n & 15)) * 8;
        *(u16x8*)&Wb[waddr] = o;
    }
}

// ---- pass 4: grouped GEMM, fragment-linear operands, global->VGPR direct.
// Every fragment load = ONE coalesced 1KB global_load_dwordx4 per wave
// (lane*16B contiguous). No LDS staging, no barriers in the K-loop:
// compiler-scheduled fine-grained vmcnt pipeline, 1-step prefetch.
__global__ __launch_bounds__(256) void moe_gemm_frag(
        const unsigned short* __restrict__ xs, const unsigned short* __restrict__ Wb,
        const float* __restrict__ bias, const int* __restrict__ counts,
        const int* __restrict__ sorted, float* __restrict__ out) {
    __shared__ int s_idx[TILE];
    int bn = blockIdx.x, bm = blockIdx.y;
    int row0 = bm * TILE;
    int total = 0, e = 0;
#pragma unroll
    for (int i = 0; i < N_EXPERTS; i++) {
        int sz = pad_tile(counts[i]);
        if (row0 >= total + sz) e = i + 1;
        total += sz;
    }
    if (row0 >= total) return;

    int tid = threadIdx.x;
    if (tid < TILE) s_idx[tid] = sorted[row0 + tid];
    // no barrier here — s_idx only needed at epilogue

    int wave = tid >> 6, lane = tid & 63;
    int wm = (wave >> 1) * 64, wn = (wave & 1) * 64;
    int lrow = lane & 15, lq = lane >> 4;

    const unsigned short* Ap = xs + (size_t)((row0 + wm) >> 4) * 8192 + lane * 8;
    const unsigned short* Bp = Wb + (size_t)e * 262144
                             + (size_t)((bn * TILE + wn) >> 4) * 8192 + lane * 8;

    f32x4 acc[4][4];
#pragma unroll
    for (int i = 0; i < 4; i++)
#pragma unroll
        for (int j = 0; j < 4; j++)
            acc[i][j] = (f32x4){0.f, 0.f, 0.f, 0.f};

    bf16x8 a0[4], b0[4], a1[4], b1[4];

#define LOADF(av, bv, ks) do {                                                  \
    _Pragma("unroll") for (int i = 0; i < 4; i++)                               \
        av[i] = *(const bf16x8*)(Ap + i * 8192 + (ks) * 512);                   \
    _Pragma("unroll") for (int j = 0; j < 4; j++)                               \
        bv[j] = *(const bf16x8*)(Bp + j * 8192 + (ks) * 512);                   \
} while (0)
#define MFMAF(av, bv) do {                                                      \
    _Pragma("unroll") for (int i = 0; i < 4; i++)                               \
    _Pragma("unroll") for (int j = 0; j < 4; j++)                               \
        acc[i][j] = __builtin_amdgcn_mfma_f32_16x16x32_bf16(                    \
            av[i], bv[j], acc[i][j], 0, 0, 0);                                  \
} while (0)

    LOADF(a0, b0, 0);
#pragma unroll 1
    for (int ks = 0; ks < 16; ks += 2) {
        LOADF(a1, b1, ks + 1);
        MFMAF(a0, b0);
        LOADF(a0, b0, ks + 2);   // ks=16 over-reads 1 rowtile: lands in Wb/sorted (mapped), unused
        MFMAF(a1, b1);
    }
#undef LOADF
#undef MFMAF

    __syncthreads();   // s_idx visible (writes happened before K-loop)

    // epilogue: bias + scatter rows back by token id
    // C/D layout: col = lane&15 (n), row = (lane>>4)*4 + reg (m)
#pragma unroll
    for (int j = 0; j < 4; j++) {
        int ng = bn * TILE + wn + 16 * j + lrow;
        float bv = bias[e * D + ng];
#pragma unroll
        for (int i = 0; i < 4; i++) {
#pragma unroll
            for (int r = 0; r < 4; r++) {
                int mrow = wm + 16 * i + lq * 4 + r;
                int tok = s_idx[mrow];
                if (tok >= 0)
                    out[(size_t)tok * D + ng] = acc[i][j][r] + bv;
            }
        }
    }
}

// ---- fallback (small ws): fp32-load GEMM ----
__global__ __launch_bounds__(256) void moe_gemm_f32(
        const float* __restrict__ x, const float* __restrict__ W,
        const float* __restrict__ bias, const int* __restrict__ counts,
        const int* __restrict__ sorted, float* __restrict__ out) {
    __shared__ int s_idx[TILE];
    __shared__ unsigned short sA[TILE][64 + 8];
    __shared__ unsigned short sB[TILE][64 + 8];

    int bm = blockIdx.x, bn = blockIdx.y;
    int row0 = bm * TILE;
    int total = 0, e = 0;
#pragma unroll
    for (int i = 0; i < N_EXPERTS; i++) {
        int sz = pad_tile(counts[i]);
        if (row0 >= total + sz) e = i + 1;
        total += sz;
    }
    if (row0 >= total) return;

    int tid = threadIdx.x;
    if (tid < TILE) s_idx[tid] = sorted[row0 + tid];
    __syncthreads();

    const float* Wp = W + (size_t)e * D * D + (size_t)(bn * TILE) * D;

    f32x4 acc[4][4];
#pragma unroll
    for (int i = 0; i < 4; i++)
#pragma unroll
        for (int j = 0; j < 4; j++)
            acc[i][j] = (f32x4){0.f, 0.f, 0.f, 0.f};

    int wave = tid >> 6, lane = tid & 63;
    int wm = (wave >> 1) * 64, wn = (wave & 1) * 64;
    int lrow = lane & 15, lq = lane >> 4;

    for (int kk = 0; kk < D; kk += 64) {
#pragma unroll
        for (int i = 0; i < 8; i++) {
            int flat = tid + i * 256;
            int r = flat >> 4, c = (flat & 15) << 2;
            int tok = s_idx[r];
            float4 v = make_float4(0.f, 0.f, 0.f, 0.f);
            if (tok >= 0) v = *(const float4*)(x + (size_t)tok * D + kk + c);
            ushort4 w4;
            w4.x = f2bf(v.x); w4.y = f2bf(v.y); w4.z = f2bf(v.z); w4.w = f2bf(v.w);
            *(ushort4*)&sA[r][c] = w4;
        }
#pragma unroll
        for (int i = 0; i < 8; i++) {
            int flat = tid + i * 256;
            int r = flat >> 4, c = (flat & 15) << 2;
            float4 v = *(const float4*)(Wp + (size_t)r * D + kk + c);
            ushort4 w4;
            w4.x = f2bf(v.x); w4.y = f2bf(v.y); w4.z = f2bf(v.z); w4.w = f2bf(v.w);
            *(ushort4*)&sB[r][c] = w4;
        }
        __syncthreads();
#pragma unroll
        for (int ks = 0; ks < 2; ks++) {
            bf16x8 af[4], bfr[4];
#pragma unroll
            for (int i = 0; i < 4; i++)
                af[i] = *(const bf16x8*)&sA[wm + 16 * i + lrow][ks * 32 + lq * 8];
#pragma unroll
            for (int j = 0; j < 4; j++)
                bfr[j] = *(const bf16x8*)&sB[wn + 16 * j + lrow][ks * 32 + lq * 8];
#pragma unroll
            for (int i = 0; i < 4; i++)
#pragma unroll
                for (int j = 0; j < 4; j++)
                    acc[i][j] = __builtin_amdgcn_mfma_f32_16x16x32_bf16(
                        af[i], bfr[j], acc[i][j], 0, 0, 0);
        }
        __syncthreads();
    }

#pragma unroll
    for (int j = 0; j < 4; j++) {
        int ng = bn * TILE + wn + 16 * j + lrow;
        float bv = bias[e * D + ng];
#pragma unroll
        for (int i = 0; i < 4; i++) {
#pragma unroll
            for (int r = 0; r < 4; r++) {
                int mrow = wm + 16 * i + lq * 4 + r;
                int tok = s_idx[mrow];
                if (tok >= 0)
                    out[(size_t)tok * D + ng] = acc[i][j][r] + bv;
            }
        }
    }
}

extern "C" void kernel_launch(void* const* d_in, const int* in_sizes, int n_in,
                              void* d_out, int out_size, void* d_ws, size_t ws_size,
                              hipStream_t stream) {
    const float* x    = (const float*)d_in[0];
    const int*   part = (const int*)d_in[1];
    const float* W    = (const float*)d_in[2];
    const float* b    = (const float*)d_in[3];
    float* out = (float*)d_out;

    const size_t xs_elems = (size_t)SORT_CAP * D;        // bf16
    const size_t wb_elems = (size_t)N_EXPERTS * D * D;   // bf16
    const size_t fast_bytes = (xs_elems + wb_elems) * 2 + SORT_CAP * 4 + 32 * 4;

    if (ws_size >= fast_bytes) {
        unsigned short* xs = (unsigned short*)d_ws;
        unsigned short* Wb = xs + xs_elems;
        int* sorted = (int*)(Wb + wb_elems);   // after Wb: GEMM over-read lands here (mapped)
        int* counts = sorted + SORT_CAP;
        int* fill   = counts + N_EXPERTS;

        hipMemsetAsync(sorted, 0xFF, SORT_CAP * sizeof(int), stream);
        hipMemsetAsync(counts, 0, 2 * N_EXPERTS * sizeof(int), stream);

        hist_kernel<<<64, 256, 0, stream>>>(part, counts);
        scatter_kernel<<<(T_TOKENS + 255) / 256, 256, 0, stream>>>(part, counts, fill, sorted);
        convert_kernel<<<GCX_BLOCKS + WCV_BLOCKS, 256, 0, stream>>>(x, W, sorted, counts, xs, Wb);

        dim3 grid(D / TILE, MAX_MTILES);   // bn fastest: n-tiles of one m-tile adjacent
        moe_gemm_frag<<<grid, 256, 0, stream>>>(xs, Wb, b, counts, sorted, out);
    } else {
        int* sorted = (int*)d_ws;
        int* counts = sorted + SORT_CAP;
        int* fill   = counts + N_EXPERTS;

        hipMemsetAsync(sorted, 0xFF, SORT_CAP * sizeof(int), stream);
        hipMemsetAsync(counts, 0, 2 * N_EXPERTS * sizeof(int), stream);

        hist_kernel<<<64, 256, 0, stream>>>(part, counts);
        scatter_kernel<<<(T_TOKENS + 255) / 256, 256, 0, stream>>>(part, counts, fill, sorted);

        dim3 grid(MAX_MTILES, D / TILE);
        moe_gemm_f32<<<grid, 256, 0, stream>>>(x, W, b, counts, sorted, out);
    }
}